// Round 1
// baseline (599.579 us; speedup 1.0000x reference)
//
#include <hip/hip_runtime.h>
#include <hip/hip_bf16.h>

typedef float f32x4 __attribute__((ext_vector_type(4)));
typedef __bf16 bf16x8 __attribute__((ext_vector_type(8)));

// ---- constants for this problem ----
// B=4, S=1024, dim=2048, H=16, D=128, T=1024, KV=T+S=2048, M=B*S=4096
#define DIMK 2048

__device__ __forceinline__ unsigned short f2bf(float f) {
    union { float f; unsigned int u; } v; v.f = f;
    unsigned int r = v.u + 0x7fffu + ((v.u >> 16) & 1u);
    return (unsigned short)(r >> 16);
}

// ---------------- cache copy: k_cache/v_cache -> d_out k/v regions ----------------
__global__ __launch_bounds__(256) void copy_cache(
    const float* __restrict__ kc, const float* __restrict__ vc,
    float* __restrict__ kout, float* __restrict__ vout)
{
    size_t i4 = (size_t)blockIdx.x * 256 + threadIdx.x;   // 0 .. 2097151 (float4 units)
    const float* src = blockIdx.y ? vc : kc;
    float* dst = blockIdx.y ? vout : kout;
    size_t e = i4 * 4;                 // element in [B,H,1024,128]
    size_t bh = e >> 17;               // / (1024*128)
    size_t rem = e & 131071;
    f32x4 v = *(const f32x4*)(src + e);
    *(f32x4*)(dst + (bh << 18) + rem) = v;   // [B,H,2048,128], rows 0..1023
}

// ---------------- fp32 -> bf16 convert ----------------
__global__ __launch_bounds__(256) void f32_to_bf16(
    const float* __restrict__ src, unsigned short* __restrict__ dst, int n4)
{
    int i = blockIdx.x * 256 + threadIdx.x;
    if (i >= n4) return;
    f32x4 v = *(const f32x4*)(src + (size_t)i * 4);
    ushort4 pk = { f2bf(v[0]), f2bf(v[1]), f2bf(v[2]), f2bf(v[3]) };
    *(ushort4*)(dst + (size_t)i * 4) = pk;
}

// ---------------- GEMM: Y[m,n] = sum_k A[m,k]*W[n,k] + bias[n] ----------------
// 128x128 tile, BK=32, 4 waves (2x2), each wave 64x64 via 4x4 frags of 16x16x32.
// MODE 0: write bf16 to ws Q [B,H,S,D];  MODE 1: write fp32 to KV region rows 1024+;
// MODE 2: write fp32 row-major [m,n].
template<int MODE, bool ABF16, bool BBF16>
__global__ __launch_bounds__(256) void gemm_bt(
    const void* __restrict__ Ag, const void* __restrict__ Wg,
    const float* __restrict__ bias, void* __restrict__ dst)
{
    const int tid = threadIdx.x;
    const int lane = tid & 63;
    const int w = tid >> 6;
    const int g = lane >> 4;
    const int c = lane & 15;
    const int wr = w >> 1, wc = w & 1;
    const int m0 = blockIdx.y * 128;
    const int n0 = blockIdx.x * 128;

    __shared__ unsigned short As[128 * 40];   // padded stride 40 (80B, 16B-aligned rows)
    __shared__ unsigned short Bs[128 * 40];

    f32x4 acc[4][4];
    #pragma unroll
    for (int i = 0; i < 4; ++i)
        #pragma unroll
        for (int j = 0; j < 4; ++j)
            acc[i][j] = f32x4{0.f, 0.f, 0.f, 0.f};

    for (int k0 = 0; k0 < DIMK; k0 += 32) {
        __syncthreads();
        // ---- stage A tile (128 x 32) ----
        if constexpr (ABF16) {
            const unsigned short* A16 = (const unsigned short*)Ag;
            #pragma unroll
            for (int r = 0; r < 2; ++r) {
                int e8 = r * 256 + tid;
                int row = e8 >> 2, col = (e8 & 3) << 3;
                *(uint4*)(&As[row * 40 + col]) =
                    *(const uint4*)(A16 + (size_t)(m0 + row) * DIMK + k0 + col);
            }
        } else {
            const float* Af = (const float*)Ag;
            #pragma unroll
            for (int r = 0; r < 4; ++r) {
                int e4 = r * 256 + tid;
                int row = e4 >> 3, col = (e4 & 7) << 2;
                f32x4 v = *(const f32x4*)(Af + (size_t)(m0 + row) * DIMK + k0 + col);
                ushort4 pk = { f2bf(v[0]), f2bf(v[1]), f2bf(v[2]), f2bf(v[3]) };
                *(ushort4*)(&As[row * 40 + col]) = pk;
            }
        }
        // ---- stage B tile (W rows n0..n0+127, 128 x 32) ----
        if constexpr (BBF16) {
            const unsigned short* W16 = (const unsigned short*)Wg;
            #pragma unroll
            for (int r = 0; r < 2; ++r) {
                int e8 = r * 256 + tid;
                int row = e8 >> 2, col = (e8 & 3) << 3;
                *(uint4*)(&Bs[row * 40 + col]) =
                    *(const uint4*)(W16 + (size_t)(n0 + row) * DIMK + k0 + col);
            }
        } else {
            const float* Wf = (const float*)Wg;
            #pragma unroll
            for (int r = 0; r < 4; ++r) {
                int e4 = r * 256 + tid;
                int row = e4 >> 3, col = (e4 & 7) << 2;
                f32x4 v = *(const f32x4*)(Wf + (size_t)(n0 + row) * DIMK + k0 + col);
                ushort4 pk = { f2bf(v[0]), f2bf(v[1]), f2bf(v[2]), f2bf(v[3]) };
                *(ushort4*)(&Bs[row * 40 + col]) = pk;
            }
        }
        __syncthreads();

        bf16x8 af[4], bfr[4];
        #pragma unroll
        for (int i = 0; i < 4; ++i)
            af[i] = *(const bf16x8*)(&As[(wr * 64 + i * 16 + c) * 40 + g * 8]);
        #pragma unroll
        for (int i = 0; i < 4; ++i)
            bfr[i] = *(const bf16x8*)(&Bs[(wc * 64 + i * 16 + c) * 40 + g * 8]);
        #pragma unroll
        for (int i = 0; i < 4; ++i)
            #pragma unroll
            for (int j = 0; j < 4; ++j)
                acc[i][j] = __builtin_amdgcn_mfma_f32_16x16x32_bf16(af[i], bfr[j], acc[i][j], 0, 0, 0);
    }

    // ---- epilogue: C/D layout col=lane&15, row=(lane>>4)*4+reg ----
    #pragma unroll
    for (int j = 0; j < 4; ++j) {
        const int n = n0 + wc * 64 + j * 16 + c;
        const float bn = bias[n];
        #pragma unroll
        for (int i = 0; i < 4; ++i) {
            #pragma unroll
            for (int tq = 0; tq < 4; ++tq) {
                const int m = m0 + wr * 64 + i * 16 + g * 4 + tq;
                float y = acc[i][j][tq] + bn;
                if constexpr (MODE == 0) {
                    int b = m >> 10, s = m & 1023;
                    int hh = n >> 7, d = n & 127;
                    ((unsigned short*)dst)[((((size_t)b * 16 + hh) << 10) + s) * 128 + d] = f2bf(y);
                } else if constexpr (MODE == 1) {
                    int b = m >> 10, s = m & 1023;
                    int hh = n >> 7, d = n & 127;
                    ((float*)dst)[(((size_t)b * 16 + hh) * 2048 + 1024 + s) * 128 + d] = y;
                } else {
                    ((float*)dst)[(size_t)m * 2048 + n] = y;
                }
            }
        }
    }
}

// ---------------- flash attention ----------------
// grid (8 q-tiles, 64 bh). 4 waves x 32 q-rows each, KVBLK=64, D=128.
__global__ __launch_bounds__(256) void attn(
    const unsigned short* __restrict__ Qbf,
    const float* __restrict__ Kf, const float* __restrict__ Vf,
    unsigned short* __restrict__ ctx)
{
    const int qt = blockIdx.x;
    const int bh = blockIdx.y;
    const int b = bh >> 4, h = bh & 15;
    const int tid = threadIdx.x;
    const int lane = tid & 63;
    const int w = tid >> 6;
    const int g = lane >> 4;
    const int c = lane & 15;

    __shared__ unsigned short Ks[64 * 136];   // [kv][d], stride 136
    __shared__ unsigned short Vt[128 * 72];   // [d][kv], stride 72
    __shared__ unsigned short Ps[4 * 32 * 72];// per-wave P [32][64], stride 72

    // Q fragments: rows w*32+m2*16+c, k = kk*32+g*8
    bf16x8 aq[2][4];
    const unsigned short* Qb = Qbf + ((size_t)bh * 1024 + qt * 128) * 128;
    #pragma unroll
    for (int m2 = 0; m2 < 2; ++m2)
        #pragma unroll
        for (int kk = 0; kk < 4; ++kk)
            aq[m2][kk] = *(const bf16x8*)(Qb + (w * 32 + m2 * 16 + c) * 128 + kk * 32 + g * 8);

    f32x4 od[2][8];
    #pragma unroll
    for (int m2 = 0; m2 < 2; ++m2)
        #pragma unroll
        for (int nf = 0; nf < 8; ++nf)
            od[m2][nf] = f32x4{0.f, 0.f, 0.f, 0.f};
    float mrow[2][4], lrow[2][4];
    #pragma unroll
    for (int m2 = 0; m2 < 2; ++m2)
        #pragma unroll
        for (int j = 0; j < 4; ++j) { mrow[m2][j] = -1e30f; lrow[m2][j] = 0.f; }

    const float* Kb = Kf + (size_t)bh * 2048 * 128;
    const float* Vb = Vf + (size_t)bh * 2048 * 128;
    const int ntiles = (1024 + (qt + 1) * 128) >> 6;   // 18 + 2*qt
    const float scale2 = 0.08838834764831845f * 1.44269504088896f; // 1/sqrt(128)*log2(e)

    for (int t = 0; t < ntiles; ++t) {
        __syncthreads();
        // stage K (64x128 fp32 -> bf16, row-major)
        const float* Kt = Kb + (size_t)t * 64 * 128;
        #pragma unroll
        for (int r = 0; r < 8; ++r) {
            int e4 = r * 256 + tid;
            int kv = e4 >> 5, d0 = (e4 & 31) << 2;
            f32x4 v = *(const f32x4*)(Kt + kv * 128 + d0);
            ushort4 pk = { f2bf(v[0]), f2bf(v[1]), f2bf(v[2]), f2bf(v[3]) };
            *(ushort4*)(&Ks[kv * 136 + d0]) = pk;
        }
        // stage V transposed (Vt[d][kv]); per-lane-contiguous global (L1 absorbs)
        const float* Vg = Vb + (size_t)t * 64 * 128;
        #pragma unroll
        for (int r = 0; r < 8; ++r) {
            int e4 = tid * 8 + r;
            int kv = e4 >> 5, d0 = (e4 & 31) << 2;
            f32x4 v = *(const f32x4*)(Vg + kv * 128 + d0);
            #pragma unroll
            for (int i = 0; i < 4; ++i)
                Vt[(d0 + i) * 72 + kv] = f2bf(v[i]);
        }
        __syncthreads();

        // QK^T: sc[m2][n], cols = t*64 + n*16 + c, rows = qtile rows
        f32x4 sc[2][4];
        #pragma unroll
        for (int m2 = 0; m2 < 2; ++m2)
            #pragma unroll
            for (int n = 0; n < 4; ++n)
                sc[m2][n] = f32x4{0.f, 0.f, 0.f, 0.f};
        #pragma unroll
        for (int kk = 0; kk < 4; ++kk) {
            bf16x8 bk[4];
            #pragma unroll
            for (int n = 0; n < 4; ++n)
                bk[n] = *(const bf16x8*)(&Ks[(n * 16 + c) * 136 + kk * 32 + g * 8]);
            #pragma unroll
            for (int m2 = 0; m2 < 2; ++m2)
                #pragma unroll
                for (int n = 0; n < 4; ++n)
                    sc[m2][n] = __builtin_amdgcn_mfma_f32_16x16x32_bf16(aq[m2][kk], bk[n], sc[m2][n], 0, 0, 0);
        }

        // online softmax (exp2 domain)
        const int kvbase = t * 64;
        #pragma unroll
        for (int m2 = 0; m2 < 2; ++m2) {
            #pragma unroll
            for (int j = 0; j < 4; ++j) {
                const int qg = qt * 128 + w * 32 + m2 * 16 + g * 4 + j;
                const int lim = qg + 1024;
                float rmax = -1e30f;
                #pragma unroll
                for (int n = 0; n < 4; ++n) {
                    float s = sc[m2][n][j] * scale2;
                    if (kvbase + n * 16 + c > lim) s = -1e30f;
                    sc[m2][n][j] = s;
                    rmax = fmaxf(rmax, s);
                }
                #pragma unroll
                for (int off = 1; off < 16; off <<= 1)
                    rmax = fmaxf(rmax, __shfl_xor(rmax, off));
                float mold = mrow[m2][j];
                float mnew = fmaxf(mold, rmax);
                mrow[m2][j] = mnew;
                float fs = exp2f(mold - mnew);
                float rsum = 0.f;
                #pragma unroll
                for (int n = 0; n < 4; ++n) {
                    float p = exp2f(sc[m2][n][j] - mnew);
                    sc[m2][n][j] = p;
                    rsum += p;
                }
                #pragma unroll
                for (int off = 1; off < 16; off <<= 1)
                    rsum += __shfl_xor(rsum, off);
                lrow[m2][j] = lrow[m2][j] * fs + rsum;
                #pragma unroll
                for (int nf = 0; nf < 8; ++nf)
                    od[m2][nf][j] *= fs;
            }
        }

        // P -> LDS (bf16), wave-private
        unsigned short* Pw = &Ps[w * 32 * 72];
        #pragma unroll
        for (int m2 = 0; m2 < 2; ++m2)
            #pragma unroll
            for (int n = 0; n < 4; ++n)
                #pragma unroll
                for (int j = 0; j < 4; ++j)
                    Pw[(m2 * 16 + g * 4 + j) * 72 + n * 16 + c] = f2bf(sc[m2][n][j]);

        // PV: od += P[32x64] * V[64x128]
        #pragma unroll
        for (int kk = 0; kk < 2; ++kk) {
            bf16x8 ap0 = *(const bf16x8*)(&Ps[(w * 32 + c) * 72 + kk * 32 + g * 8]);
            bf16x8 ap1 = *(const bf16x8*)(&Ps[(w * 32 + 16 + c) * 72 + kk * 32 + g * 8]);
            #pragma unroll
            for (int nf = 0; nf < 8; ++nf) {
                bf16x8 bv = *(const bf16x8*)(&Vt[(nf * 16 + c) * 72 + kk * 32 + g * 8]);
                od[0][nf] = __builtin_amdgcn_mfma_f32_16x16x32_bf16(ap0, bv, od[0][nf], 0, 0, 0);
                od[1][nf] = __builtin_amdgcn_mfma_f32_16x16x32_bf16(ap1, bv, od[1][nf], 0, 0, 0);
            }
        }
    }

    // epilogue: ctx[b][s][h*128+d] bf16
    #pragma unroll
    for (int m2 = 0; m2 < 2; ++m2) {
        #pragma unroll
        for (int j = 0; j < 4; ++j) {
            const int qg = qt * 128 + w * 32 + m2 * 16 + g * 4 + j;
            const float rl = 1.0f / lrow[m2][j];
            #pragma unroll
            for (int nf = 0; nf < 8; ++nf) {
                const int d = nf * 16 + c;
                ctx[((size_t)b * 1024 + qg) * 2048 + h * 128 + d] = f2bf(od[m2][nf][j] * rl);
            }
        }
    }
}

extern "C" void kernel_launch(void* const* d_in, const int* in_sizes, int n_in,
                              void* d_out, int out_size, void* d_ws, size_t ws_size,
                              hipStream_t stream) {
    const float* x  = (const float*)d_in[0];
    const float* kc = (const float*)d_in[1];
    const float* vc = (const float*)d_in[2];
    const float* Wq = (const float*)d_in[3];
    const float* bq = (const float*)d_in[4];
    const float* Wk = (const float*)d_in[5];
    const float* bk = (const float*)d_in[6];
    const float* Wv = (const float*)d_in[7];
    const float* bv = (const float*)d_in[8];
    const float* Wo = (const float*)d_in[9];
    const float* bo = (const float*)d_in[10];

    float* outp = (float*)d_out;
    float* kout = outp + (size_t)8388608;   // k region [4,16,2048,128]
    float* vout = outp + (size_t)25165824;  // v region

    unsigned short* Qbf = (unsigned short*)d_ws;          // [4,16,1024,128] bf16
    unsigned short* ctx = Qbf + (size_t)8388608;          // [4,1024,2048]  bf16

    copy_cache<<<dim3(8192, 2), 256, 0, stream>>>(kc, vc, kout, vout);

    const bool big = ws_size >= (size_t)83886080;  // room for bf16 copies of x + 4 weights
    if (big) {
        unsigned short* xbf = ctx + (size_t)8388608;
        unsigned short* Wqb = xbf + (size_t)8388608;
        unsigned short* Wkb = Wqb + (size_t)4194304;
        unsigned short* Wvb = Wkb + (size_t)4194304;
        unsigned short* Wob = Wvb + (size_t)4194304;
        f32_to_bf16<<<8192, 256, 0, stream>>>(x,  xbf, 2097152);
        f32_to_bf16<<<4096, 256, 0, stream>>>(Wq, Wqb, 1048576);
        f32_to_bf16<<<4096, 256, 0, stream>>>(Wk, Wkb, 1048576);
        f32_to_bf16<<<4096, 256, 0, stream>>>(Wv, Wvb, 1048576);
        f32_to_bf16<<<4096, 256, 0, stream>>>(Wo, Wob, 1048576);
        gemm_bt<0, true, true><<<dim3(16, 32), 256, 0, stream>>>(xbf, Wqb, bq, Qbf);
        gemm_bt<1, true, true><<<dim3(16, 32), 256, 0, stream>>>(xbf, Wkb, bk, kout);
        gemm_bt<1, true, true><<<dim3(16, 32), 256, 0, stream>>>(xbf, Wvb, bv, vout);
        attn<<<dim3(8, 64), 256, 0, stream>>>(Qbf, kout, vout, ctx);
        gemm_bt<2, true, true><<<dim3(16, 32), 256, 0, stream>>>(ctx, Wob, bo, outp);
    } else {
        gemm_bt<0, false, false><<<dim3(16, 32), 256, 0, stream>>>(x, Wq, bq, Qbf);
        gemm_bt<1, false, false><<<dim3(16, 32), 256, 0, stream>>>(x, Wk, bk, kout);
        gemm_bt<1, false, false><<<dim3(16, 32), 256, 0, stream>>>(x, Wv, bv, vout);
        attn<<<dim3(8, 64), 256, 0, stream>>>(Qbf, kout, vout, ctx);
        gemm_bt<2, true, false><<<dim3(16, 32), 256, 0, stream>>>(ctx, Wo, bo, outp);
    }
}